// Round 1
// baseline (956.372 us; speedup 1.0000x reference)
//
#include <hip/hip_runtime.h>

#define N_NODES 100000
#define N_EDGES 1600000
#define DIM 64
#define NLAYER 4
#define NGRAPH 128
#define BN_EPS 1e-5f

// ---------------- CSR build ----------------

__global__ void k_hist(const int* __restrict__ ei, int* __restrict__ cnt) {
    int e = blockIdx.x * blockDim.x + threadIdx.x;
    if (e < N_EDGES) atomicAdd(&cnt[ei[N_EDGES + e]], 1);
}

__global__ void k_scan1(const int* __restrict__ cnt, int* __restrict__ exc,
                        int* __restrict__ bsums) {
    __shared__ int s[256];
    int i = blockIdx.x * 256 + threadIdx.x;
    int v = (i < N_NODES) ? cnt[i] : 0;
    s[threadIdx.x] = v;
    __syncthreads();
    for (int off = 1; off < 256; off <<= 1) {
        int t = (threadIdx.x >= off) ? s[threadIdx.x - off] : 0;
        __syncthreads();
        s[threadIdx.x] += t;
        __syncthreads();
    }
    if (i < N_NODES) exc[i] = s[threadIdx.x] - v;
    if (threadIdx.x == 255) bsums[blockIdx.x] = s[255];
}

__global__ void k_scan2(const int* __restrict__ bsums, int* __restrict__ boffs, int nb) {
    __shared__ int s[512];
    int v = ((int)threadIdx.x < nb) ? bsums[threadIdx.x] : 0;
    s[threadIdx.x] = v;
    __syncthreads();
    for (int off = 1; off < 512; off <<= 1) {
        int t = (threadIdx.x >= off) ? s[threadIdx.x - off] : 0;
        __syncthreads();
        s[threadIdx.x] += t;
        __syncthreads();
    }
    if ((int)threadIdx.x < nb) boffs[threadIdx.x] = s[threadIdx.x] - v;
}

__global__ void k_scan3(int* __restrict__ exc, const int* __restrict__ boffs) {
    int i = blockIdx.x * 256 + threadIdx.x;
    if (i < N_NODES) exc[i] += boffs[blockIdx.x];
}

__global__ void k_fill(const int* __restrict__ ei, const int* __restrict__ rowptr,
                       int* __restrict__ cursor, int* __restrict__ csr) {
    int e = blockIdx.x * blockDim.x + threadIdx.x;
    if (e < N_EDGES) {
        int d = ei[N_EDGES + e];
        int pos = rowptr[d] + atomicAdd(&cursor[d], 1);
        csr[pos] = ei[e];
    }
}

// inv_deg per node; inv graph count per graph (batch is sorted -> binary search)
__global__ void k_prep(const int* __restrict__ cnt, const int* __restrict__ batch,
                       float* __restrict__ invdeg, float* __restrict__ invg) {
    int i = blockIdx.x * blockDim.x + threadIdx.x;
    if (i < N_NODES) invdeg[i] = 1.0f / (float)max(cnt[i], 1);
    if (i < NGRAPH) {
        int key = i, lo = 0, hi = N_NODES;
        while (lo < hi) { int m = (lo + hi) >> 1; if (batch[m] < key) lo = m + 1; else hi = m; }
        int a = lo;
        key = i + 1; lo = 0; hi = N_NODES;
        while (lo < hi) { int m = (lo + hi) >> 1; if (batch[m] < key) lo = m + 1; else hi = m; }
        invg[i] = 1.0f / (float)max(lo - a, 1);
    }
}

// ---------------- Layer pass A: aggregate + GEMV(W1) + BN moments ----------------

__global__ __launch_bounds__(256)
void k_passA(const float* __restrict__ h, const float* __restrict__ W1,
             const float* __restrict__ b1,
             const int* __restrict__ rowptr, const int* __restrict__ cnt,
             const int* __restrict__ csr, const float* __restrict__ invdeg,
             float* __restrict__ z, float* __restrict__ colsum,
             float* __restrict__ colsumsq) {
    int lane = threadIdx.x & 63;
    int wid = (blockIdx.x * blockDim.x + threadIdx.x) >> 6;
    int nwaves = (gridDim.x * blockDim.x) >> 6;

    float w[64];
#pragma unroll
    for (int k = 0; k < 64; k++) w[k] = W1[k * 64 + lane];
    float bj = b1[lane];

    float ls = 0.f, lq = 0.f;
    for (int n = wid; n < N_NODES; n += nwaves) {
        int start = rowptr[n];
        int deg = cnt[n];
        float acc = 0.f;
        int e = 0;
        for (; e + 4 <= deg; e += 4) {
            int s0 = csr[start + e], s1 = csr[start + e + 1];
            int s2 = csr[start + e + 2], s3 = csr[start + e + 3];
            float a0 = h[(long)s0 * 64 + lane];
            float a1 = h[(long)s1 * 64 + lane];
            float a2 = h[(long)s2 * 64 + lane];
            float a3 = h[(long)s3 * 64 + lane];
            acc += a0 + a1 + a2 + a3;
        }
        for (; e < deg; e++) acc += h[(long)csr[start + e] * 64 + lane];

        float t = h[(long)n * 64 + lane] + acc * invdeg[n];

        float zj = bj;
#pragma unroll
        for (int k = 0; k < 64; k++) {
            float tk = __int_as_float(__builtin_amdgcn_readlane(__float_as_int(t), k));
            zj = fmaf(tk, w[k], zj);
        }
        z[(long)n * 64 + lane] = zj;
        ls += zj;
        lq += zj * zj;
    }

    __shared__ float rs[256], rq[256];
    rs[threadIdx.x] = ls;
    rq[threadIdx.x] = lq;
    __syncthreads();
    if (threadIdx.x < 64) {
        float a = rs[threadIdx.x] + rs[threadIdx.x + 64] + rs[threadIdx.x + 128] + rs[threadIdx.x + 192];
        float b = rq[threadIdx.x] + rq[threadIdx.x + 64] + rq[threadIdx.x + 128] + rq[threadIdx.x + 192];
        atomicAdd(&colsum[threadIdx.x], a);
        atomicAdd(&colsumsq[threadIdx.x], b);
    }
}

// ---------------- BN prep (per layer; also re-zeros moment accumulators) --------

__global__ void k_bnprep(float* __restrict__ colsum, float* __restrict__ colsumsq,
                         const float* __restrict__ gamma, const float* __restrict__ beta,
                         float* __restrict__ scale, float* __restrict__ shift) {
    int j = threadIdx.x;  // 64 threads
    float invn = 1.0f / (float)N_NODES;
    float mu = colsum[j] * invn;
    float var = colsumsq[j] * invn - mu * mu;
    float rsg = rsqrtf(var + BN_EPS);
    float sc = gamma[j] * rsg;
    scale[j] = sc;
    shift[j] = beta[j] - mu * sc;
    colsum[j] = 0.f;
    colsumsq[j] = 0.f;
}

// ---------------- Layer pass B: BN + ReLU + GEMV(W2) + pools ----------------

__global__ __launch_bounds__(256)
void k_passB(const float* __restrict__ z, const float* __restrict__ W2,
             const float* __restrict__ b2, const float* __restrict__ scale,
             const float* __restrict__ shift, const int* __restrict__ batch,
             float* __restrict__ hout, float* __restrict__ node_pool,
             float* __restrict__ gacc, int first) {
    int lane = threadIdx.x & 63;
    int wid = (blockIdx.x * blockDim.x + threadIdx.x) >> 6;
    int nwaves = (gridDim.x * blockDim.x) >> 6;
    int chunk = (N_NODES + nwaves - 1) / nwaves;
    int n0 = wid * chunk;
    int n1 = min(N_NODES, n0 + chunk);

    float w[64];
#pragma unroll
    for (int k = 0; k < 64; k++) w[k] = W2[k * 64 + lane];
    float bj = b2[lane], sc = scale[lane], sh = shift[lane];

    int curg = -1;
    float ga = 0.f;
    for (int n = n0; n < n1; n++) {
        float zj = z[(long)n * 64 + lane];
        float r = fmaxf(fmaf(zj, sc, sh), 0.f);
        float hj = bj;
#pragma unroll
        for (int k = 0; k < 64; k++) {
            float rk = __int_as_float(__builtin_amdgcn_readlane(__float_as_int(r), k));
            hj = fmaf(rk, w[k], hj);
        }
        hout[(long)n * 64 + lane] = hj;
        if (first) node_pool[(long)n * 64 + lane] = hj;
        else node_pool[(long)n * 64 + lane] += hj;
        int g = batch[n];
        if (g != curg) {
            if (curg >= 0) atomicAdd(&gacc[curg * 64 + lane], ga);
            ga = 0.f;
            curg = g;
        }
        ga += hj;
    }
    if (curg >= 0) atomicAdd(&gacc[curg * 64 + lane], ga);
}

__global__ void k_gfinal(const float* __restrict__ gacc, const float* __restrict__ invg,
                         float* __restrict__ gout) {
    int i = blockIdx.x * blockDim.x + threadIdx.x;
    if (i < NGRAPH * 64) gout[i] = gacc[i] * invg[i >> 6];
}

// ---------------- launch ----------------

extern "C" void kernel_launch(void* const* d_in, const int* in_sizes, int n_in,
                              void* d_out, int out_size, void* d_ws, size_t ws_size,
                              hipStream_t stream) {
    (void)in_sizes; (void)n_in; (void)out_size; (void)ws_size;
    const float* x     = (const float*)d_in[0];
    const int*   ei    = (const int*)d_in[1];
    const int*   batch = (const int*)d_in[2];
    const float* W1    = (const float*)d_in[3];
    const float* b1    = (const float*)d_in[4];
    const float* gamma = (const float*)d_in[5];
    const float* beta  = (const float*)d_in[6];
    const float* W2    = (const float*)d_in[7];
    const float* b2    = (const float*)d_in[8];
    float* out = (float*)d_out;  // [N*64] node_pool, then [G*64] g_pool

    // workspace layout (element offsets, 4 B units)
    size_t o = 0;
    size_t o_cnt     = o; o += N_NODES;
    size_t o_cursor  = o; o += N_NODES;
    size_t o_colsum  = o; o += 64;
    size_t o_colsq   = o; o += 64;
    size_t o_gacc    = o; o += (size_t)NGRAPH * 64;
    size_t zero_elems = o;                      // everything above must start at 0
    size_t o_rowptr  = o; o += N_NODES;
    size_t o_bsums   = o; o += 512;
    size_t o_boffs   = o; o += 512;
    size_t o_invdeg  = o; o += N_NODES;
    size_t o_invg    = o; o += NGRAPH;
    size_t o_scale   = o; o += 64;
    size_t o_shift   = o; o += 64;
    size_t o_csr     = o; o += N_EDGES;
    size_t o_bufA    = o; o += (size_t)N_NODES * 64;
    size_t o_bufB    = o; o += (size_t)N_NODES * 64;

    int*   wsi = (int*)d_ws;
    float* wsf = (float*)d_ws;
    int*   cnt    = wsi + o_cnt;
    int*   cursor = wsi + o_cursor;
    float* colsum = wsf + o_colsum;
    float* colsq  = wsf + o_colsq;
    float* gacc   = wsf + o_gacc;
    int*   rowptr = wsi + o_rowptr;
    int*   bsums  = wsi + o_bsums;
    int*   boffs  = wsi + o_boffs;
    float* invdeg = wsf + o_invdeg;
    float* invg   = wsf + o_invg;
    float* scale  = wsf + o_scale;
    float* shift  = wsf + o_shift;
    int*   csr    = wsi + o_csr;
    float* bufA   = wsf + o_bufA;
    float* bufB   = wsf + o_bufB;

    hipMemsetAsync(d_ws, 0, zero_elems * 4, stream);

    const int eb = (N_EDGES + 255) / 256;
    const int nb = (N_NODES + 255) / 256;  // 391 <= 512

    k_hist<<<eb, 256, 0, stream>>>(ei, cnt);
    k_scan1<<<nb, 256, 0, stream>>>(cnt, rowptr, bsums);
    k_scan2<<<1, 512, 0, stream>>>(bsums, boffs, nb);
    k_scan3<<<nb, 256, 0, stream>>>(rowptr, boffs);
    k_prep<<<nb, 256, 0, stream>>>(cnt, batch, invdeg, invg);
    k_fill<<<eb, 256, 0, stream>>>(ei, rowptr, cursor, csr);

    const int gridA = 2048, gridB = 1024;
    for (int l = 0; l < NLAYER; l++) {
        const float* h_in = (l == 0) ? x : bufB;
        k_passA<<<gridA, 256, 0, stream>>>(h_in, W1 + l * 4096, b1 + l * 64,
                                           rowptr, cnt, csr, invdeg,
                                           bufA, colsum, colsq);
        k_bnprep<<<1, 64, 0, stream>>>(colsum, colsq, gamma + l * 64, beta + l * 64,
                                       scale, shift);
        k_passB<<<gridB, 256, 0, stream>>>(bufA, W2 + l * 4096, b2 + l * 64,
                                           scale, shift, batch,
                                           bufB, out, gacc, (l == 0) ? 1 : 0);
    }
    k_gfinal<<<32, 256, 0, stream>>>(gacc, invg, out + (size_t)N_NODES * 64);
}

// Round 2
// 841.078 us; speedup vs baseline: 1.1371x; 1.1371x over previous
//
#include <hip/hip_runtime.h>

#define N_NODES 100000
#define N_EDGES 1600000
#define DIM 64
#define NLAYER 4
#define NGRAPH 128
#define BN_EPS 1e-5f

// ---------------- CSR build ----------------

__global__ void k_hist(const int* __restrict__ ei, int* __restrict__ cnt) {
    int e = blockIdx.x * blockDim.x + threadIdx.x;
    if (e < N_EDGES) atomicAdd(&cnt[ei[N_EDGES + e]], 1);
}

__global__ void k_scan1(const int* __restrict__ cnt, int* __restrict__ exc,
                        int* __restrict__ bsums) {
    __shared__ int s[256];
    int i = blockIdx.x * 256 + threadIdx.x;
    int v = (i < N_NODES) ? cnt[i] : 0;
    s[threadIdx.x] = v;
    __syncthreads();
    for (int off = 1; off < 256; off <<= 1) {
        int t = (threadIdx.x >= off) ? s[threadIdx.x - off] : 0;
        __syncthreads();
        s[threadIdx.x] += t;
        __syncthreads();
    }
    if (i < N_NODES) exc[i] = s[threadIdx.x] - v;
    if (threadIdx.x == 255) bsums[blockIdx.x] = s[255];
}

__global__ void k_scan2(const int* __restrict__ bsums, int* __restrict__ boffs, int nb) {
    __shared__ int s[512];
    int v = ((int)threadIdx.x < nb) ? bsums[threadIdx.x] : 0;
    s[threadIdx.x] = v;
    __syncthreads();
    for (int off = 1; off < 512; off <<= 1) {
        int t = (threadIdx.x >= off) ? s[threadIdx.x - off] : 0;
        __syncthreads();
        s[threadIdx.x] += t;
        __syncthreads();
    }
    if ((int)threadIdx.x < nb) boffs[threadIdx.x] = s[threadIdx.x] - v;
}

__global__ void k_scan3(int* __restrict__ exc, const int* __restrict__ boffs) {
    int i = blockIdx.x * 256 + threadIdx.x;
    if (i < N_NODES) exc[i] += boffs[blockIdx.x];
}

__global__ void k_fill(const int* __restrict__ ei, const int* __restrict__ rowptr,
                       int* __restrict__ cursor, int* __restrict__ csr) {
    int e = blockIdx.x * blockDim.x + threadIdx.x;
    if (e < N_EDGES) {
        int d = ei[N_EDGES + e];
        int pos = rowptr[d] + atomicAdd(&cursor[d], 1);
        csr[pos] = ei[e];
    }
}

__global__ void k_prep(const int* __restrict__ cnt, const int* __restrict__ batch,
                       float* __restrict__ invdeg, float* __restrict__ invg) {
    int i = blockIdx.x * blockDim.x + threadIdx.x;
    if (i < N_NODES) invdeg[i] = 1.0f / (float)max(cnt[i], 1);
    if (i < NGRAPH) {
        int key = i, lo = 0, hi = N_NODES;
        while (lo < hi) { int m = (lo + hi) >> 1; if (batch[m] < key) lo = m + 1; else hi = m; }
        int a = lo;
        key = i + 1; lo = 0; hi = N_NODES;
        while (lo < hi) { int m = (lo + hi) >> 1; if (batch[m] < key) lo = m + 1; else hi = m; }
        invg[i] = 1.0f / (float)max(lo - a, 1);
    }
}

// ---------------- Layer pass A: aggregate + GEMV(W1) + BN moments ----------------
// One wave per contiguous node chunk; lane = feature column.
// wid forced uniform -> rowptr/cnt/csr loads are scalar (s_load), gathers get
// SGPR base + lane*4 voffset. W1 column held in 64 VGPRs (launch_bounds(256,4)
// allows up to 128 VGPRs).

__global__ __launch_bounds__(256, 4)
void k_passA(const float* __restrict__ h, const float* __restrict__ W1,
             const float* __restrict__ b1,
             const int* __restrict__ rowptr, const int* __restrict__ cnt,
             const int* __restrict__ csr, const float* __restrict__ invdeg,
             float* __restrict__ z, float* __restrict__ colsum,
             float* __restrict__ colsumsq) {
    const int lane = threadIdx.x & 63;
    int wid_raw = (blockIdx.x << 2) | (threadIdx.x >> 6);
    const int wid = __builtin_amdgcn_readfirstlane(wid_raw);
    const int nwaves = gridDim.x << 2;
    const int chunk = (N_NODES + nwaves - 1) / nwaves;
    const int n0 = wid * chunk;
    const int n1 = min(N_NODES, n0 + chunk);

    float w[64];
#pragma unroll
    for (int k = 0; k < 64; k++) w[k] = W1[k * 64 + lane];
    const float bj = b1[lane];

    float ls = 0.f, lq = 0.f;
    for (int n = n0; n < n1; n++) {
        const int start = rowptr[n];
        const int deg = cnt[n];
        const float self = h[(size_t)n * 64 + lane];
        const float idg = invdeg[n];
        float acc = 0.f;
        int e = 0;
        for (; e + 8 <= deg; e += 8) {
            const int* cp = csr + start + e;
            int i0 = cp[0], i1 = cp[1], i2 = cp[2], i3 = cp[3];
            int i4 = cp[4], i5 = cp[5], i6 = cp[6], i7 = cp[7];
            float a0 = h[(size_t)i0 * 64 + lane];
            float a1 = h[(size_t)i1 * 64 + lane];
            float a2 = h[(size_t)i2 * 64 + lane];
            float a3 = h[(size_t)i3 * 64 + lane];
            float a4 = h[(size_t)i4 * 64 + lane];
            float a5 = h[(size_t)i5 * 64 + lane];
            float a6 = h[(size_t)i6 * 64 + lane];
            float a7 = h[(size_t)i7 * 64 + lane];
            acc += ((a0 + a1) + (a2 + a3)) + ((a4 + a5) + (a6 + a7));
        }
        for (; e < deg; e++) acc += h[(size_t)csr[start + e] * 64 + lane];

        float t = fmaf(acc, idg, self);

        float zj = bj;
#pragma unroll
        for (int k = 0; k < 64; k++) {
            float tk = __int_as_float(__builtin_amdgcn_readlane(__float_as_int(t), k));
            zj = fmaf(tk, w[k], zj);
        }
        z[(size_t)n * 64 + lane] = zj;
        ls += zj;
        lq += zj * zj;
    }

    __shared__ float rs[256], rq[256];
    rs[threadIdx.x] = ls;
    rq[threadIdx.x] = lq;
    __syncthreads();
    if (threadIdx.x < 64) {
        float a = rs[threadIdx.x] + rs[threadIdx.x + 64] + rs[threadIdx.x + 128] + rs[threadIdx.x + 192];
        float b = rq[threadIdx.x] + rq[threadIdx.x + 64] + rq[threadIdx.x + 128] + rq[threadIdx.x + 192];
        atomicAdd(&colsum[threadIdx.x], a);
        atomicAdd(&colsumsq[threadIdx.x], b);
    }
}

// ---------------- BN prep (per layer; also re-zeros moment accumulators) --------

__global__ void k_bnprep(float* __restrict__ colsum, float* __restrict__ colsumsq,
                         const float* __restrict__ gamma, const float* __restrict__ beta,
                         float* __restrict__ scale, float* __restrict__ shift) {
    int j = threadIdx.x;  // 64 threads
    float invn = 1.0f / (float)N_NODES;
    float mu = colsum[j] * invn;
    float var = colsumsq[j] * invn - mu * mu;
    float rsg = rsqrtf(var + BN_EPS);
    float sc = gamma[j] * rsg;
    scale[j] = sc;
    shift[j] = beta[j] - mu * sc;
    colsum[j] = 0.f;
    colsumsq[j] = 0.f;
}

// ---------------- Layer pass B: BN + ReLU + GEMV(W2) + pools ----------------

__global__ __launch_bounds__(256, 4)
void k_passB(const float* __restrict__ z, const float* __restrict__ W2,
             const float* __restrict__ b2, const float* __restrict__ scale,
             const float* __restrict__ shift, const int* __restrict__ batch,
             float* __restrict__ hout, float* __restrict__ node_pool,
             float* __restrict__ gacc, int first) {
    const int lane = threadIdx.x & 63;
    int wid_raw = (blockIdx.x << 2) | (threadIdx.x >> 6);
    const int wid = __builtin_amdgcn_readfirstlane(wid_raw);
    const int nwaves = gridDim.x << 2;
    const int chunk = (N_NODES + nwaves - 1) / nwaves;
    const int n0 = wid * chunk;
    const int n1 = min(N_NODES, n0 + chunk);

    float w[64];
#pragma unroll
    for (int k = 0; k < 64; k++) w[k] = W2[k * 64 + lane];
    const float bj = b2[lane], sc = scale[lane], sh = shift[lane];

    int curg = -1;
    float ga = 0.f;
    for (int n = n0; n < n1; n++) {
        float zj = z[(size_t)n * 64 + lane];
        float r = fmaxf(fmaf(zj, sc, sh), 0.f);
        float hj = bj;
#pragma unroll
        for (int k = 0; k < 64; k++) {
            float rk = __int_as_float(__builtin_amdgcn_readlane(__float_as_int(r), k));
            hj = fmaf(rk, w[k], hj);
        }
        hout[(size_t)n * 64 + lane] = hj;
        if (first) node_pool[(size_t)n * 64 + lane] = hj;
        else node_pool[(size_t)n * 64 + lane] += hj;
        int g = batch[n];
        if (g != curg) {
            if (curg >= 0) atomicAdd(&gacc[curg * 64 + lane], ga);
            ga = 0.f;
            curg = g;
        }
        ga += hj;
    }
    if (curg >= 0) atomicAdd(&gacc[curg * 64 + lane], ga);
}

__global__ void k_gfinal(const float* __restrict__ gacc, const float* __restrict__ invg,
                         float* __restrict__ gout) {
    int i = blockIdx.x * blockDim.x + threadIdx.x;
    if (i < NGRAPH * 64) gout[i] = gacc[i] * invg[i >> 6];
}

// ---------------- launch ----------------

extern "C" void kernel_launch(void* const* d_in, const int* in_sizes, int n_in,
                              void* d_out, int out_size, void* d_ws, size_t ws_size,
                              hipStream_t stream) {
    (void)in_sizes; (void)n_in; (void)out_size; (void)ws_size;
    const float* x     = (const float*)d_in[0];
    const int*   ei    = (const int*)d_in[1];
    const int*   batch = (const int*)d_in[2];
    const float* W1    = (const float*)d_in[3];
    const float* b1    = (const float*)d_in[4];
    const float* gamma = (const float*)d_in[5];
    const float* beta  = (const float*)d_in[6];
    const float* W2    = (const float*)d_in[7];
    const float* b2    = (const float*)d_in[8];
    float* out = (float*)d_out;  // [N*64] node_pool, then [G*64] g_pool

    size_t o = 0;
    size_t o_cnt     = o; o += N_NODES;
    size_t o_cursor  = o; o += N_NODES;
    size_t o_colsum  = o; o += 64;
    size_t o_colsq   = o; o += 64;
    size_t o_gacc    = o; o += (size_t)NGRAPH * 64;
    size_t zero_elems = o;
    size_t o_rowptr  = o; o += N_NODES;
    size_t o_bsums   = o; o += 512;
    size_t o_boffs   = o; o += 512;
    size_t o_invdeg  = o; o += N_NODES;
    size_t o_invg    = o; o += NGRAPH;
    size_t o_scale   = o; o += 64;
    size_t o_shift   = o; o += 64;
    size_t o_csr     = o; o += N_EDGES;
    size_t o_bufA    = o; o += (size_t)N_NODES * 64;
    size_t o_bufB    = o; o += (size_t)N_NODES * 64;

    int*   wsi = (int*)d_ws;
    float* wsf = (float*)d_ws;
    int*   cnt    = wsi + o_cnt;
    int*   cursor = wsi + o_cursor;
    float* colsum = wsf + o_colsum;
    float* colsq  = wsf + o_colsq;
    float* gacc   = wsf + o_gacc;
    int*   rowptr = wsi + o_rowptr;
    int*   bsums  = wsi + o_bsums;
    int*   boffs  = wsi + o_boffs;
    float* invdeg = wsf + o_invdeg;
    float* invg   = wsf + o_invg;
    float* scale  = wsf + o_scale;
    float* shift  = wsf + o_shift;
    int*   csr    = wsi + o_csr;
    float* bufA   = wsf + o_bufA;
    float* bufB   = wsf + o_bufB;

    hipMemsetAsync(d_ws, 0, zero_elems * 4, stream);

    const int eb = (N_EDGES + 255) / 256;
    const int nb = (N_NODES + 255) / 256;  // 391 <= 512

    k_hist<<<eb, 256, 0, stream>>>(ei, cnt);
    k_scan1<<<nb, 256, 0, stream>>>(cnt, rowptr, bsums);
    k_scan2<<<1, 512, 0, stream>>>(bsums, boffs, nb);
    k_scan3<<<nb, 256, 0, stream>>>(rowptr, boffs);
    k_prep<<<nb, 256, 0, stream>>>(cnt, batch, invdeg, invg);
    k_fill<<<eb, 256, 0, stream>>>(ei, rowptr, cursor, csr);

    const int gridA = 2048, gridB = 2048;
    for (int l = 0; l < NLAYER; l++) {
        const float* h_in = (l == 0) ? x : bufB;
        k_passA<<<gridA, 256, 0, stream>>>(h_in, W1 + l * 4096, b1 + l * 64,
                                           rowptr, cnt, csr, invdeg,
                                           bufA, colsum, colsq);
        k_bnprep<<<1, 64, 0, stream>>>(colsum, colsq, gamma + l * 64, beta + l * 64,
                                       scale, shift);
        k_passB<<<gridB, 256, 0, stream>>>(bufA, W2 + l * 4096, b2 + l * 64,
                                           scale, shift, batch,
                                           bufB, out, gacc, (l == 0) ? 1 : 0);
    }
    k_gfinal<<<32, 256, 0, stream>>>(gacc, invg, out + (size_t)N_NODES * 64);
}

// Round 3
// 801.102 us; speedup vs baseline: 1.1938x; 1.0499x over previous
//
#include <hip/hip_runtime.h>

#define N_NODES 100000
#define N_EDGES 1600000
#define DIM 64
#define NLAYER 4
#define NGRAPH 128
#define BN_EPS 1e-5f

// ---------------- CSR build ----------------

__global__ void k_hist(const int* __restrict__ ei, int* __restrict__ cnt) {
    int e = blockIdx.x * blockDim.x + threadIdx.x;
    if (e < N_EDGES) atomicAdd(&cnt[ei[N_EDGES + e]], 1);
}

__global__ void k_scan1(const int* __restrict__ cnt, int* __restrict__ exc,
                        int* __restrict__ bsums) {
    __shared__ int s[256];
    int i = blockIdx.x * 256 + threadIdx.x;
    int v = (i < N_NODES) ? cnt[i] : 0;
    s[threadIdx.x] = v;
    __syncthreads();
    for (int off = 1; off < 256; off <<= 1) {
        int t = (threadIdx.x >= off) ? s[threadIdx.x - off] : 0;
        __syncthreads();
        s[threadIdx.x] += t;
        __syncthreads();
    }
    if (i < N_NODES) exc[i] = s[threadIdx.x] - v;
    if (threadIdx.x == 255) bsums[blockIdx.x] = s[255];
}

__global__ void k_scan2(const int* __restrict__ bsums, int* __restrict__ boffs, int nb) {
    __shared__ int s[512];
    int v = ((int)threadIdx.x < nb) ? bsums[threadIdx.x] : 0;
    s[threadIdx.x] = v;
    __syncthreads();
    for (int off = 1; off < 512; off <<= 1) {
        int t = (threadIdx.x >= off) ? s[threadIdx.x - off] : 0;
        __syncthreads();
        s[threadIdx.x] += t;
        __syncthreads();
    }
    if ((int)threadIdx.x < nb) boffs[threadIdx.x] = s[threadIdx.x] - v;
}

__global__ void k_scan3(int* __restrict__ exc, const int* __restrict__ boffs) {
    int i = blockIdx.x * 256 + threadIdx.x;
    if (i < N_NODES) exc[i] += boffs[blockIdx.x];
}

__global__ void k_fill(const int* __restrict__ ei, const int* __restrict__ rowptr,
                       int* __restrict__ cursor, int* __restrict__ csr) {
    int e = blockIdx.x * blockDim.x + threadIdx.x;
    if (e < N_EDGES) {
        int d = ei[N_EDGES + e];
        int pos = rowptr[d] + atomicAdd(&cursor[d], 1);
        csr[pos] = ei[e];
    }
}

__global__ void k_prep(const int* __restrict__ cnt, const int* __restrict__ batch,
                       float* __restrict__ invdeg, float* __restrict__ invg) {
    int i = blockIdx.x * blockDim.x + threadIdx.x;
    if (i < N_NODES) invdeg[i] = 1.0f / (float)max(cnt[i], 1);
    if (i < NGRAPH) {
        int key = i, lo = 0, hi = N_NODES;
        while (lo < hi) { int m = (lo + hi) >> 1; if (batch[m] < key) lo = m + 1; else hi = m; }
        int a = lo;
        key = i + 1; lo = 0; hi = N_NODES;
        while (lo < hi) { int m = (lo + hi) >> 1; if (batch[m] < key) lo = m + 1; else hi = m; }
        invg[i] = 1.0f / (float)max(lo - a, 1);
    }
}

// ---------------- Layer pass A: aggregate + GEMV(W1) + BN moments ----------------
// One wave per contiguous node chunk; lane = feature column. wid uniform ->
// csr/rowptr/cnt loads scalar. W1 column pinned into 64 VGPRs via empty asm
// (prevents the allocator from rematerializing the loads inside the loop;
// without the pin the compiler emits 64 VMEM loads per node = 1.6 GB/pass L1).

__global__ __launch_bounds__(256, 4)
void k_passA(const float* __restrict__ h, const float* __restrict__ W1,
             const float* __restrict__ b1,
             const int* __restrict__ rowptr, const int* __restrict__ cnt,
             const int* __restrict__ csr, const float* __restrict__ invdeg,
             float* __restrict__ z, float* __restrict__ colsum,
             float* __restrict__ colsumsq) {
    const int lane = threadIdx.x & 63;
    int wid_raw = (blockIdx.x << 2) | (threadIdx.x >> 6);
    const int wid = __builtin_amdgcn_readfirstlane(wid_raw);
    const int nwaves = gridDim.x << 2;
    const int chunk = (N_NODES + nwaves - 1) / nwaves;
    const int n0 = wid * chunk;
    const int n1 = min(N_NODES, n0 + chunk);

    float w[64];
#pragma unroll
    for (int k = 0; k < 64; k++) w[k] = W1[k * 64 + lane];
#pragma unroll
    for (int k = 0; k < 64; k++) asm("" : "+v"(w[k]));   // pin in VGPRs
    const float bj = b1[lane];

    float ls = 0.f, lq = 0.f;
    for (int n = n0; n < n1; n++) {
        const int start = rowptr[n];
        const int deg = cnt[n];
        const float self = h[(size_t)n * 64 + lane];
        const float idg = invdeg[n];
        float acc = 0.f;
        int e = 0;
        for (; e + 8 <= deg; e += 8) {
            const int* cp = csr + start + e;
            int i0 = cp[0], i1 = cp[1], i2 = cp[2], i3 = cp[3];
            int i4 = cp[4], i5 = cp[5], i6 = cp[6], i7 = cp[7];
            float a0 = h[(size_t)i0 * 64 + lane];
            float a1 = h[(size_t)i1 * 64 + lane];
            float a2 = h[(size_t)i2 * 64 + lane];
            float a3 = h[(size_t)i3 * 64 + lane];
            float a4 = h[(size_t)i4 * 64 + lane];
            float a5 = h[(size_t)i5 * 64 + lane];
            float a6 = h[(size_t)i6 * 64 + lane];
            float a7 = h[(size_t)i7 * 64 + lane];
            acc += ((a0 + a1) + (a2 + a3)) + ((a4 + a5) + (a6 + a7));
        }
        if (e < deg) {
            // masked batch: all tail gathers issued together (no serial
            // load->add latency chain); clamped indices are safe re-reads.
            const int* cp = csr + start;
            const int last = deg - 1;
            const int rem = deg - e;  // 1..7
            int i0 = cp[e];
            int i1 = cp[min(e + 1, last)];
            int i2 = cp[min(e + 2, last)];
            int i3 = cp[min(e + 3, last)];
            int i4 = cp[min(e + 4, last)];
            int i5 = cp[min(e + 5, last)];
            int i6 = cp[min(e + 6, last)];
            float a0 = h[(size_t)i0 * 64 + lane];
            float a1 = h[(size_t)i1 * 64 + lane];
            float a2 = h[(size_t)i2 * 64 + lane];
            float a3 = h[(size_t)i3 * 64 + lane];
            float a4 = h[(size_t)i4 * 64 + lane];
            float a5 = h[(size_t)i5 * 64 + lane];
            float a6 = h[(size_t)i6 * 64 + lane];
            acc += a0;
            acc += (1 < rem) ? a1 : 0.f;
            acc += (2 < rem) ? a2 : 0.f;
            acc += (3 < rem) ? a3 : 0.f;
            acc += (4 < rem) ? a4 : 0.f;
            acc += (5 < rem) ? a5 : 0.f;
            acc += (6 < rem) ? a6 : 0.f;
        }

        float t = fmaf(acc, idg, self);

        float zj = bj;
#pragma unroll
        for (int k = 0; k < 64; k++) {
            float tk = __int_as_float(__builtin_amdgcn_readlane(__float_as_int(t), k));
            zj = fmaf(tk, w[k], zj);
        }
        z[(size_t)n * 64 + lane] = zj;
        ls += zj;
        lq += zj * zj;
    }

    __shared__ float rs[256], rq[256];
    rs[threadIdx.x] = ls;
    rq[threadIdx.x] = lq;
    __syncthreads();
    if (threadIdx.x < 64) {
        float a = rs[threadIdx.x] + rs[threadIdx.x + 64] + rs[threadIdx.x + 128] + rs[threadIdx.x + 192];
        float b = rq[threadIdx.x] + rq[threadIdx.x + 64] + rq[threadIdx.x + 128] + rq[threadIdx.x + 192];
        atomicAdd(&colsum[threadIdx.x], a);
        atomicAdd(&colsumsq[threadIdx.x], b);
    }
}

// ---------------- BN prep (per layer; also re-zeros moment accumulators) --------

__global__ void k_bnprep(float* __restrict__ colsum, float* __restrict__ colsumsq,
                         const float* __restrict__ gamma, const float* __restrict__ beta,
                         float* __restrict__ scale, float* __restrict__ shift) {
    int j = threadIdx.x;  // 64 threads
    float invn = 1.0f / (float)N_NODES;
    float mu = colsum[j] * invn;
    float var = colsumsq[j] * invn - mu * mu;
    float rsg = rsqrtf(var + BN_EPS);
    float sc = gamma[j] * rsg;
    scale[j] = sc;
    shift[j] = beta[j] - mu * sc;
    colsum[j] = 0.f;
    colsumsq[j] = 0.f;
}

// ---------------- Layer pass B: BN + ReLU + GEMV(W2) + pools ----------------

__global__ __launch_bounds__(256, 4)
void k_passB(const float* __restrict__ z, const float* __restrict__ W2,
             const float* __restrict__ b2, const float* __restrict__ scale,
             const float* __restrict__ shift, const int* __restrict__ batch,
             float* __restrict__ hout, float* __restrict__ node_pool,
             float* __restrict__ gacc, int first) {
    const int lane = threadIdx.x & 63;
    int wid_raw = (blockIdx.x << 2) | (threadIdx.x >> 6);
    const int wid = __builtin_amdgcn_readfirstlane(wid_raw);
    const int nwaves = gridDim.x << 2;
    const int chunk = (N_NODES + nwaves - 1) / nwaves;
    const int n0 = wid * chunk;
    const int n1 = min(N_NODES, n0 + chunk);

    float w[64];
#pragma unroll
    for (int k = 0; k < 64; k++) w[k] = W2[k * 64 + lane];
#pragma unroll
    for (int k = 0; k < 64; k++) asm("" : "+v"(w[k]));   // pin in VGPRs
    const float bj = b2[lane], sc = scale[lane], sh = shift[lane];

    int curg = -1;
    float ga = 0.f;
    for (int n = n0; n < n1; n++) {
        float zj = z[(size_t)n * 64 + lane];
        float r = fmaxf(fmaf(zj, sc, sh), 0.f);
        float hj = bj;
#pragma unroll
        for (int k = 0; k < 64; k++) {
            float rk = __int_as_float(__builtin_amdgcn_readlane(__float_as_int(r), k));
            hj = fmaf(rk, w[k], hj);
        }
        hout[(size_t)n * 64 + lane] = hj;
        if (first) node_pool[(size_t)n * 64 + lane] = hj;
        else node_pool[(size_t)n * 64 + lane] += hj;
        int g = batch[n];
        if (g != curg) {
            if (curg >= 0) atomicAdd(&gacc[curg * 64 + lane], ga);
            ga = 0.f;
            curg = g;
        }
        ga += hj;
    }
    if (curg >= 0) atomicAdd(&gacc[curg * 64 + lane], ga);
}

__global__ void k_gfinal(const float* __restrict__ gacc, const float* __restrict__ invg,
                         float* __restrict__ gout) {
    int i = blockIdx.x * blockDim.x + threadIdx.x;
    if (i < NGRAPH * 64) gout[i] = gacc[i] * invg[i >> 6];
}

// ---------------- launch ----------------

extern "C" void kernel_launch(void* const* d_in, const int* in_sizes, int n_in,
                              void* d_out, int out_size, void* d_ws, size_t ws_size,
                              hipStream_t stream) {
    (void)in_sizes; (void)n_in; (void)out_size; (void)ws_size;
    const float* x     = (const float*)d_in[0];
    const int*   ei    = (const int*)d_in[1];
    const int*   batch = (const int*)d_in[2];
    const float* W1    = (const float*)d_in[3];
    const float* b1    = (const float*)d_in[4];
    const float* gamma = (const float*)d_in[5];
    const float* beta  = (const float*)d_in[6];
    const float* W2    = (const float*)d_in[7];
    const float* b2    = (const float*)d_in[8];
    float* out = (float*)d_out;  // [N*64] node_pool, then [G*64] g_pool

    size_t o = 0;
    size_t o_cnt     = o; o += N_NODES;
    size_t o_cursor  = o; o += N_NODES;
    size_t o_colsum  = o; o += 64;
    size_t o_colsq   = o; o += 64;
    size_t o_gacc    = o; o += (size_t)NGRAPH * 64;
    size_t zero_elems = o;
    size_t o_rowptr  = o; o += N_NODES;
    size_t o_bsums   = o; o += 512;
    size_t o_boffs   = o; o += 512;
    size_t o_invdeg  = o; o += N_NODES;
    size_t o_invg    = o; o += NGRAPH;
    size_t o_scale   = o; o += 64;
    size_t o_shift   = o; o += 64;
    size_t o_csr     = o; o += N_EDGES;
    size_t o_bufA    = o; o += (size_t)N_NODES * 64;
    size_t o_bufB    = o; o += (size_t)N_NODES * 64;

    int*   wsi = (int*)d_ws;
    float* wsf = (float*)d_ws;
    int*   cnt    = wsi + o_cnt;
    int*   cursor = wsi + o_cursor;
    float* colsum = wsf + o_colsum;
    float* colsq  = wsf + o_colsq;
    float* gacc   = wsf + o_gacc;
    int*   rowptr = wsi + o_rowptr;
    int*   bsums  = wsi + o_bsums;
    int*   boffs  = wsi + o_boffs;
    float* invdeg = wsf + o_invdeg;
    float* invg   = wsf + o_invg;
    float* scale  = wsf + o_scale;
    float* shift  = wsf + o_shift;
    int*   csr    = wsi + o_csr;
    float* bufA   = wsf + o_bufA;
    float* bufB   = wsf + o_bufB;

    hipMemsetAsync(d_ws, 0, zero_elems * 4, stream);

    const int eb = (N_EDGES + 255) / 256;
    const int nb = (N_NODES + 255) / 256;  // 391 <= 512

    k_hist<<<eb, 256, 0, stream>>>(ei, cnt);
    k_scan1<<<nb, 256, 0, stream>>>(cnt, rowptr, bsums);
    k_scan2<<<1, 512, 0, stream>>>(bsums, boffs, nb);
    k_scan3<<<nb, 256, 0, stream>>>(rowptr, boffs);
    k_prep<<<nb, 256, 0, stream>>>(cnt, batch, invdeg, invg);
    k_fill<<<eb, 256, 0, stream>>>(ei, rowptr, cursor, csr);

    const int gridA = 2048, gridB = 2048;
    for (int l = 0; l < NLAYER; l++) {
        const float* h_in = (l == 0) ? x : bufB;
        k_passA<<<gridA, 256, 0, stream>>>(h_in, W1 + l * 4096, b1 + l * 64,
                                           rowptr, cnt, csr, invdeg,
                                           bufA, colsum, colsq);
        k_bnprep<<<1, 64, 0, stream>>>(colsum, colsq, gamma + l * 64, beta + l * 64,
                                       scale, shift);
        k_passB<<<gridB, 256, 0, stream>>>(bufA, W2 + l * 4096, b2 + l * 64,
                                           scale, shift, batch,
                                           bufB, out, gacc, (l == 0) ? 1 : 0);
    }
    k_gfinal<<<32, 256, 0, stream>>>(gacc, invg, out + (size_t)N_NODES * 64);
}

// Round 4
// 705.981 us; speedup vs baseline: 1.3547x; 1.1347x over previous
//
#include <hip/hip_runtime.h>

#define N_NODES 100000
#define N_EDGES 1600000
#define DIM 64
#define NLAYER 4
#define NGRAPH 128
#define BN_EPS 1e-5f

// ---------------- CSR build ----------------
// Rank trick: the histogram atomic already yields each edge's rank within its
// dst row -- store it, so the fill pass needs NO atomics (the scattered-atomic
// pass costs ~23 fabric-cycles per op; doing it once instead of twice).

__global__ void k_hist(const int* __restrict__ ei, int* __restrict__ cnt,
                       int* __restrict__ rank) {
    int e = blockIdx.x * blockDim.x + threadIdx.x;
    if (e < N_EDGES) {
        int d = ei[N_EDGES + e];
        rank[e] = atomicAdd(&cnt[d], 1);
    }
}

__global__ void k_scan1(const int* __restrict__ cnt, int* __restrict__ exc,
                        int* __restrict__ bsums) {
    __shared__ int s[256];
    int i = blockIdx.x * 256 + threadIdx.x;
    int v = (i < N_NODES) ? cnt[i] : 0;
    s[threadIdx.x] = v;
    __syncthreads();
    for (int off = 1; off < 256; off <<= 1) {
        int t = (threadIdx.x >= off) ? s[threadIdx.x - off] : 0;
        __syncthreads();
        s[threadIdx.x] += t;
        __syncthreads();
    }
    if (i < N_NODES) exc[i] = s[threadIdx.x] - v;
    if (threadIdx.x == 255) bsums[blockIdx.x] = s[255];
}

__global__ void k_scan2(const int* __restrict__ bsums, int* __restrict__ boffs, int nb) {
    __shared__ int s[512];
    int v = ((int)threadIdx.x < nb) ? bsums[threadIdx.x] : 0;
    s[threadIdx.x] = v;
    __syncthreads();
    for (int off = 1; off < 512; off <<= 1) {
        int t = (threadIdx.x >= off) ? s[threadIdx.x - off] : 0;
        __syncthreads();
        s[threadIdx.x] += t;
        __syncthreads();
    }
    if ((int)threadIdx.x < nb) boffs[threadIdx.x] = s[threadIdx.x] - v;
}

__global__ void k_scan3(int* __restrict__ exc, const int* __restrict__ boffs) {
    int i = blockIdx.x * 256 + threadIdx.x;
    if (i < N_NODES) exc[i] += boffs[blockIdx.x];
}

__global__ void k_fill(const int* __restrict__ ei, const int* __restrict__ rowptr,
                       const int* __restrict__ rank, int* __restrict__ csr) {
    int e = blockIdx.x * blockDim.x + threadIdx.x;
    if (e < N_EDGES) {
        int d = ei[N_EDGES + e];
        csr[rowptr[d] + rank[e]] = ei[e];   // no atomics; rowptr (400KB) L2-resident
    }
}

__global__ void k_prep(const int* __restrict__ cnt, const int* __restrict__ batch,
                       float* __restrict__ invdeg, float* __restrict__ invg) {
    int i = blockIdx.x * blockDim.x + threadIdx.x;
    if (i < N_NODES) invdeg[i] = 1.0f / (float)max(cnt[i], 1);
    if (i < NGRAPH) {
        int key = i, lo = 0, hi = N_NODES;
        while (lo < hi) { int m = (lo + hi) >> 1; if (batch[m] < key) lo = m + 1; else hi = m; }
        int a = lo;
        key = i + 1; lo = 0; hi = N_NODES;
        while (lo < hi) { int m = (lo + hi) >> 1; if (batch[m] < key) lo = m + 1; else hi = m; }
        invg[i] = 1.0f / (float)max(lo - a, 1);
    }
}

// Drain the remaining edges [e, deg) of one node's row: full-8 batches then one
// masked batch of up to 7 (all gathers in flight together, no serial chain).
__device__ __forceinline__ float drain_gather(const float* __restrict__ h,
                                              const int* __restrict__ cp,
                                              int e, int deg, int lane) {
    float acc = 0.f;
    for (; e + 8 <= deg; e += 8) {
        int i0 = cp[e], i1 = cp[e+1], i2 = cp[e+2], i3 = cp[e+3];
        int i4 = cp[e+4], i5 = cp[e+5], i6 = cp[e+6], i7 = cp[e+7];
        float a0 = h[(size_t)i0 * 64 + lane];
        float a1 = h[(size_t)i1 * 64 + lane];
        float a2 = h[(size_t)i2 * 64 + lane];
        float a3 = h[(size_t)i3 * 64 + lane];
        float a4 = h[(size_t)i4 * 64 + lane];
        float a5 = h[(size_t)i5 * 64 + lane];
        float a6 = h[(size_t)i6 * 64 + lane];
        float a7 = h[(size_t)i7 * 64 + lane];
        acc += ((a0 + a1) + (a2 + a3)) + ((a4 + a5) + (a6 + a7));
    }
    if (e < deg) {
        const int last = deg - 1;
        const int rem = deg - e;  // 1..7
        int i0 = cp[e];
        int i1 = cp[min(e + 1, last)];
        int i2 = cp[min(e + 2, last)];
        int i3 = cp[min(e + 3, last)];
        int i4 = cp[min(e + 4, last)];
        int i5 = cp[min(e + 5, last)];
        int i6 = cp[min(e + 6, last)];
        float a0 = h[(size_t)i0 * 64 + lane];
        float a1 = h[(size_t)i1 * 64 + lane];
        float a2 = h[(size_t)i2 * 64 + lane];
        float a3 = h[(size_t)i3 * 64 + lane];
        float a4 = h[(size_t)i4 * 64 + lane];
        float a5 = h[(size_t)i5 * 64 + lane];
        float a6 = h[(size_t)i6 * 64 + lane];
        acc += a0;
        acc += (1 < rem) ? a1 : 0.f;
        acc += (2 < rem) ? a2 : 0.f;
        acc += (3 < rem) ? a3 : 0.f;
        acc += (4 < rem) ? a4 : 0.f;
        acc += (5 < rem) ? a5 : 0.f;
        acc += (6 < rem) ? a6 : 0.f;
    }
    return acc;
}

// ---------------- Layer pass A: aggregate + GEMV(W1) + BN moments ----------------
// Two nodes per wave iteration: doubles outstanding gathers (latency-bound) and
// gives two independent readlane-FMA chains in the GEMV.

#define CHUNK_A 14  // even, so the pair loop covers every wave's range exactly

__global__ __launch_bounds__(256, 4)
void k_passA(const float* __restrict__ h, const float* __restrict__ W1,
             const float* __restrict__ b1,
             const int* __restrict__ rowptr, const int* __restrict__ cnt,
             const int* __restrict__ csr, const float* __restrict__ invdeg,
             float* __restrict__ z, float* __restrict__ colsum,
             float* __restrict__ colsumsq) {
    const int lane = threadIdx.x & 63;
    int wid_raw = (blockIdx.x << 2) | (threadIdx.x >> 6);
    const int wid = __builtin_amdgcn_readfirstlane(wid_raw);
    const int n0 = wid * CHUNK_A;
    const int n1 = min(N_NODES, n0 + CHUNK_A);

    float w[64];
#pragma unroll
    for (int k = 0; k < 64; k++) w[k] = W1[k * 64 + lane];
#pragma unroll
    for (int k = 0; k < 64; k++) asm("" : "+v"(w[k]));   // pin in VGPRs
    const float bj = b1[lane];

    float ls = 0.f, lq = 0.f;
    int n = n0;
    for (; n + 2 <= n1; n += 2) {
        const int sa = rowptr[n],     da = cnt[n];
        const int sb = rowptr[n + 1], db = cnt[n + 1];
        const float selfa = h[(size_t)n * 64 + lane];
        const float selfb = h[(size_t)(n + 1) * 64 + lane];
        const float idga = invdeg[n], idgb = invdeg[n + 1];
        const int* __restrict__ ca = csr + sa;
        const int* __restrict__ cb = csr + sb;

        float aa = 0.f, ab = 0.f;
        const int m = min(da, db);
        int e = 0;
        for (; e + 4 <= m; e += 4) {
            int ia0 = ca[e], ia1 = ca[e+1], ia2 = ca[e+2], ia3 = ca[e+3];
            int ib0 = cb[e], ib1 = cb[e+1], ib2 = cb[e+2], ib3 = cb[e+3];
            float va0 = h[(size_t)ia0 * 64 + lane];
            float va1 = h[(size_t)ia1 * 64 + lane];
            float va2 = h[(size_t)ia2 * 64 + lane];
            float va3 = h[(size_t)ia3 * 64 + lane];
            float vb0 = h[(size_t)ib0 * 64 + lane];
            float vb1 = h[(size_t)ib1 * 64 + lane];
            float vb2 = h[(size_t)ib2 * 64 + lane];
            float vb3 = h[(size_t)ib3 * 64 + lane];
            aa += (va0 + va1) + (va2 + va3);
            ab += (vb0 + vb1) + (vb2 + vb3);
        }
        aa += drain_gather(h, ca, e, da, lane);
        ab += drain_gather(h, cb, e, db, lane);

        float ta = fmaf(aa, idga, selfa);
        float tb = fmaf(ab, idgb, selfb);

        float za = bj, zb = bj;
#pragma unroll
        for (int k = 0; k < 64; k++) {
            float tka = __int_as_float(__builtin_amdgcn_readlane(__float_as_int(ta), k));
            float tkb = __int_as_float(__builtin_amdgcn_readlane(__float_as_int(tb), k));
            za = fmaf(tka, w[k], za);
            zb = fmaf(tkb, w[k], zb);
        }
        z[(size_t)n * 64 + lane] = za;
        z[(size_t)(n + 1) * 64 + lane] = zb;
        ls += za + zb;
        lq += za * za + zb * zb;
    }
    for (; n < n1; n++) {  // safety epilogue (unused with even CHUNK_A)
        const int start = rowptr[n];
        const int deg = cnt[n];
        const float self = h[(size_t)n * 64 + lane];
        float acc = drain_gather(h, csr + start, 0, deg, lane);
        float t = fmaf(acc, invdeg[n], self);
        float zj = bj;
#pragma unroll
        for (int k = 0; k < 64; k++) {
            float tk = __int_as_float(__builtin_amdgcn_readlane(__float_as_int(t), k));
            zj = fmaf(tk, w[k], zj);
        }
        z[(size_t)n * 64 + lane] = zj;
        ls += zj;
        lq += zj * zj;
    }

    __shared__ float rs[256], rq[256];
    rs[threadIdx.x] = ls;
    rq[threadIdx.x] = lq;
    __syncthreads();
    if (threadIdx.x < 64) {
        float a = rs[threadIdx.x] + rs[threadIdx.x + 64] + rs[threadIdx.x + 128] + rs[threadIdx.x + 192];
        float b = rq[threadIdx.x] + rq[threadIdx.x + 64] + rq[threadIdx.x + 128] + rq[threadIdx.x + 192];
        atomicAdd(&colsum[threadIdx.x], a);
        atomicAdd(&colsumsq[threadIdx.x], b);
    }
}

// ---------------- BN prep (per layer; also re-zeros moment accumulators) --------

__global__ void k_bnprep(float* __restrict__ colsum, float* __restrict__ colsumsq,
                         const float* __restrict__ gamma, const float* __restrict__ beta,
                         float* __restrict__ scale, float* __restrict__ shift) {
    int j = threadIdx.x;  // 64 threads
    float invn = 1.0f / (float)N_NODES;
    float mu = colsum[j] * invn;
    float var = colsumsq[j] * invn - mu * mu;
    float rsg = rsqrtf(var + BN_EPS);
    float sc = gamma[j] * rsg;
    scale[j] = sc;
    shift[j] = beta[j] - mu * sc;
    colsum[j] = 0.f;
    colsumsq[j] = 0.f;
}

// ---------------- Layer pass B: BN + ReLU + GEMV(W2) + pools ----------------

__global__ __launch_bounds__(256, 4)
void k_passB(const float* __restrict__ z, const float* __restrict__ W2,
             const float* __restrict__ b2, const float* __restrict__ scale,
             const float* __restrict__ shift, const int* __restrict__ batch,
             float* __restrict__ hout, float* __restrict__ node_pool,
             float* __restrict__ gacc, int first) {
    const int lane = threadIdx.x & 63;
    int wid_raw = (blockIdx.x << 2) | (threadIdx.x >> 6);
    const int wid = __builtin_amdgcn_readfirstlane(wid_raw);
    const int nwaves = gridDim.x << 2;
    const int chunk = (N_NODES + nwaves - 1) / nwaves;
    const int n0 = wid * chunk;
    const int n1 = min(N_NODES, n0 + chunk);

    float w[64];
#pragma unroll
    for (int k = 0; k < 64; k++) w[k] = W2[k * 64 + lane];
#pragma unroll
    for (int k = 0; k < 64; k++) asm("" : "+v"(w[k]));   // pin in VGPRs
    const float bj = b2[lane], sc = scale[lane], sh = shift[lane];

    int curg = -1;
    float ga = 0.f;
    for (int n = n0; n < n1; n++) {
        float zj = z[(size_t)n * 64 + lane];
        float r = fmaxf(fmaf(zj, sc, sh), 0.f);
        float hj = bj;
#pragma unroll
        for (int k = 0; k < 64; k++) {
            float rk = __int_as_float(__builtin_amdgcn_readlane(__float_as_int(r), k));
            hj = fmaf(rk, w[k], hj);
        }
        hout[(size_t)n * 64 + lane] = hj;
        if (first) node_pool[(size_t)n * 64 + lane] = hj;
        else node_pool[(size_t)n * 64 + lane] += hj;
        int g = batch[n];
        if (g != curg) {
            if (curg >= 0) atomicAdd(&gacc[curg * 64 + lane], ga);
            ga = 0.f;
            curg = g;
        }
        ga += hj;
    }
    if (curg >= 0) atomicAdd(&gacc[curg * 64 + lane], ga);
}

__global__ void k_gfinal(const float* __restrict__ gacc, const float* __restrict__ invg,
                         float* __restrict__ gout) {
    int i = blockIdx.x * blockDim.x + threadIdx.x;
    if (i < NGRAPH * 64) gout[i] = gacc[i] * invg[i >> 6];
}

// ---------------- launch ----------------

extern "C" void kernel_launch(void* const* d_in, const int* in_sizes, int n_in,
                              void* d_out, int out_size, void* d_ws, size_t ws_size,
                              hipStream_t stream) {
    (void)in_sizes; (void)n_in; (void)out_size; (void)ws_size;
    const float* x     = (const float*)d_in[0];
    const int*   ei    = (const int*)d_in[1];
    const int*   batch = (const int*)d_in[2];
    const float* W1    = (const float*)d_in[3];
    const float* b1    = (const float*)d_in[4];
    const float* gamma = (const float*)d_in[5];
    const float* beta  = (const float*)d_in[6];
    const float* W2    = (const float*)d_in[7];
    const float* b2    = (const float*)d_in[8];
    float* out = (float*)d_out;  // [N*64] node_pool, then [G*64] g_pool

    size_t o = 0;
    size_t o_cnt     = o; o += N_NODES;
    size_t o_colsum  = o; o += 64;
    size_t o_colsq   = o; o += 64;
    size_t o_gacc    = o; o += (size_t)NGRAPH * 64;
    size_t zero_elems = o;
    size_t o_rowptr  = o; o += N_NODES;
    size_t o_bsums   = o; o += 512;
    size_t o_boffs   = o; o += 512;
    size_t o_invdeg  = o; o += N_NODES;
    size_t o_invg    = o; o += NGRAPH;
    size_t o_scale   = o; o += 64;
    size_t o_shift   = o; o += 64;
    size_t o_rank    = o; o += N_EDGES;
    size_t o_csr     = o; o += N_EDGES;
    size_t o_bufA    = o; o += (size_t)N_NODES * 64;
    size_t o_bufB    = o; o += (size_t)N_NODES * 64;

    int*   wsi = (int*)d_ws;
    float* wsf = (float*)d_ws;
    int*   cnt    = wsi + o_cnt;
    float* colsum = wsf + o_colsum;
    float* colsq  = wsf + o_colsq;
    float* gacc   = wsf + o_gacc;
    int*   rowptr = wsi + o_rowptr;
    int*   bsums  = wsi + o_bsums;
    int*   boffs  = wsi + o_boffs;
    float* invdeg = wsf + o_invdeg;
    float* invg   = wsf + o_invg;
    float* scale  = wsf + o_scale;
    float* shift  = wsf + o_shift;
    int*   rank   = wsi + o_rank;
    int*   csr    = wsi + o_csr;
    float* bufA   = wsf + o_bufA;
    float* bufB   = wsf + o_bufB;

    hipMemsetAsync(d_ws, 0, zero_elems * 4, stream);

    const int eb = (N_EDGES + 255) / 256;
    const int nb = (N_NODES + 255) / 256;  // 391 <= 512

    k_hist<<<eb, 256, 0, stream>>>(ei, cnt, rank);
    k_scan1<<<nb, 256, 0, stream>>>(cnt, rowptr, bsums);
    k_scan2<<<1, 512, 0, stream>>>(bsums, boffs, nb);
    k_scan3<<<nb, 256, 0, stream>>>(rowptr, boffs);
    k_prep<<<nb, 256, 0, stream>>>(cnt, batch, invdeg, invg);
    k_fill<<<eb, 256, 0, stream>>>(ei, rowptr, rank, csr);

    const int gridA = (N_NODES + CHUNK_A * 4 - 1) / (CHUNK_A * 4);  // 1786
    const int gridB = 2048;
    for (int l = 0; l < NLAYER; l++) {
        const float* h_in = (l == 0) ? x : bufB;
        k_passA<<<gridA, 256, 0, stream>>>(h_in, W1 + l * 4096, b1 + l * 64,
                                           rowptr, cnt, csr, invdeg,
                                           bufA, colsum, colsq);
        k_bnprep<<<1, 64, 0, stream>>>(colsum, colsq, gamma + l * 64, beta + l * 64,
                                       scale, shift);
        k_passB<<<gridB, 256, 0, stream>>>(bufA, W2 + l * 4096, b2 + l * 64,
                                           scale, shift, batch,
                                           bufB, out, gacc, (l == 0) ? 1 : 0);
    }
    k_gfinal<<<32, 256, 0, stream>>>(gacc, invg, out + (size_t)N_NODES * 64);
}